// Round 9
// baseline (592.806 us; speedup 1.0000x reference)
//
#include <hip/hip_runtime.h>
#include <stdint.h>

// ---------------- common helpers ----------------
typedef __attribute__((ext_vector_type(8))) short short8;
typedef __attribute__((ext_vector_type(4))) short short4v;
typedef __attribute__((ext_vector_type(4))) float float4v;
typedef __attribute__((ext_vector_type(8))) __bf16 bf16x8;

#define NCH 8  // attention S-dim split factor

__device__ __forceinline__ float4v mfma16x16x32(short8 a, short8 b, float4v c) {
  return __builtin_amdgcn_mfma_f32_16x16x32_bf16(
      __builtin_bit_cast(bf16x8, a), __builtin_bit_cast(bf16x8, b), c, 0, 0, 0);
}

// float -> bf16 (RNE), as raw short
__device__ __forceinline__ short f2bf(float f) {
  uint32_t u = __builtin_bit_cast(uint32_t, f);
  u += 0x7fffu + ((u >> 16) & 1u);
  return (short)(u >> 16);
}

__device__ __forceinline__ float bf2f(short s) {
  return __builtin_bit_cast(float, ((uint32_t)(uint16_t)s) << 16);
}

// async 16B global->LDS. LDS dst = wave-uniform base + lane*16 at all sites.
__device__ __forceinline__ void load_lds16(const short* g, short* l) {
  __builtin_amdgcn_global_load_lds(
      (const __attribute__((address_space(1))) void*)g,
      (__attribute__((address_space(3))) void*)l, 16, 0, 0);
}

// ---------------- fused fp32 -> bf16 for lang + 4 weights ----------------
__global__ __launch_bounds__(256) void convert5(
    const float* __restrict__ sl, short* __restrict__ dl,
    const float* __restrict__ s1, short* __restrict__ d1,
    const float* __restrict__ s2, short* __restrict__ d2,
    const float* __restrict__ s3, short* __restrict__ d3,
    const float* __restrict__ s4, short* __restrict__ d4) {
  const float* src; short* dst; int n4;
  switch (blockIdx.y) {
    case 0: src = sl; dst = dl; n4 = 131072; break;
    case 1: src = s1; dst = d1; n4 = 65536; break;
    case 2: src = s2; dst = d2; n4 = 65536; break;
    case 3: src = s3; dst = d3; n4 = 65536; break;
    default: src = s4; dst = d4; n4 = 65536; break;
  }
  const int stride = gridDim.x * blockDim.x;
  for (int i = blockIdx.x * blockDim.x + threadIdx.x; i < n4; i += stride) {
    float4v v = *(const float4v*)(src + (long)i * 4);
    short4v o;
#pragma unroll
    for (int r = 0; r < 4; r++) o[r] = f2bf(v[r]);
    *(short4v*)(dst + (long)i * 4) = o;
  }
}

// ---------------- small NT GEMM (q / out projections) ----------------
// C[m,n] = scale * sum_k A[m,k]*B[n,k]; 128x128 tile, BK=32, 4 waves.
// XOR-swizzled LDS; prefetch-reordered K-loop. OUT_F32=1: C fp32; else bf16.
template <int OUT_F32>
__global__ __launch_bounds__(256) void gemm_nt(
    const short* __restrict__ A, const short* __restrict__ B,
    void* __restrict__ C, int K, int ldc, float scale) {
  __shared__ alignas(16) short lA[128 * 32];
  __shared__ alignas(16) short lB[128 * 32];
  const int tid = threadIdx.x;
  const int lane = tid & 63, w = tid >> 6;
  const int quad = lane >> 4, l16 = lane & 15;
  const int wm = w >> 1, wn = w & 1;
  const long m0 = (long)blockIdx.y * 128, n0 = (long)blockIdx.x * 128;

  float4v acc[4][4];
#pragma unroll
  for (int i = 0; i < 4; i++)
#pragma unroll
    for (int j = 0; j < 4; j++) acc[i][j] = (float4v)0.0f;

  const int srow = tid >> 2;
  const int scol = (((tid & 3) ^ ((srow >> 1) & 3))) * 8;

  load_lds16(&A[(m0 + srow) * K + scol], &lA[tid * 8]);
  load_lds16(&A[(m0 + 64 + srow) * K + scol], &lA[2048 + tid * 8]);
  load_lds16(&B[(n0 + srow) * K + scol], &lB[tid * 8]);
  load_lds16(&B[(n0 + 64 + srow) * K + scol], &lB[2048 + tid * 8]);

  for (int kt = 0; kt < K; kt += 32) {
    __syncthreads();

    short8 af[4], bf[4];
#pragma unroll
    for (int t = 0; t < 4; t++) {
      const int ra = wm * 64 + t * 16 + l16;
      const int rb = wn * 64 + t * 16 + l16;
      af[t] = *(const short8*)&lA[ra * 32 + ((quad ^ ((ra >> 1) & 3)) * 8)];
      bf[t] = *(const short8*)&lB[rb * 32 + ((quad ^ ((rb >> 1) & 3)) * 8)];
    }
    __syncthreads();

    if (kt + 32 < K) {
      load_lds16(&A[(m0 + srow) * K + kt + 32 + scol], &lA[tid * 8]);
      load_lds16(&A[(m0 + 64 + srow) * K + kt + 32 + scol], &lA[2048 + tid * 8]);
      load_lds16(&B[(n0 + srow) * K + kt + 32 + scol], &lB[tid * 8]);
      load_lds16(&B[(n0 + 64 + srow) * K + kt + 32 + scol], &lB[2048 + tid * 8]);
    }
#pragma unroll
    for (int i = 0; i < 4; i++)
#pragma unroll
      for (int j = 0; j < 4; j++)
        acc[i][j] = mfma16x16x32(af[i], bf[j], acc[i][j]);
  }

  const int cm = wm * 64 + quad * 4;
  const int cn = wn * 64 + l16;
  if (OUT_F32) {
    float* Cf = (float*)C;
#pragma unroll
    for (int i = 0; i < 4; i++)
#pragma unroll
      for (int j = 0; j < 4; j++) {
        const long gn = n0 + cn + j * 16;
#pragma unroll
        for (int r = 0; r < 4; r++)
          Cf[(m0 + cm + i * 16 + r) * (long)ldc + gn] = acc[i][j][r] * scale;
      }
  } else {
    short* Cs = (short*)C;
#pragma unroll
    for (int i = 0; i < 4; i++)
#pragma unroll
      for (int j = 0; j < 4; j++) {
        const long gn = n0 + cn + j * 16;
#pragma unroll
        for (int r = 0; r < 4; r++)
          Cs[(m0 + cm + i * 16 + r) * (long)ldc + gn] = f2bf(acc[i][j][r] * scale);
      }
  }
}

// ---------------- fused transpose + projection: out = W @ vis ----------------
// Reads vis fp32 (b,c,s) DIRECTLY (no pre-transpose). W-slab (32i x 512c)
// persistent in LDS (staged once). Per K-iter: 32c x 128s vis tile converted
// to bf16 in regs and written c-major into a ping-pong LDS tile (ONE barrier
// per iter; skewed pitch ro(c)=c*136+(c>>3)*8 for bank spread). 2-deep reg
// pipeline on the vis stream. 256 thr, 4 waves side-by-side along s (wave tile
// 32i x 32s, acc 16 AGPR). grid = (i/32=16, s/128=32, Bg).
// TRANS=1: k[s][i]; TRANS=0: v[i][s].
template <int TRANS>
__global__ __launch_bounds__(256) void proj_kv(
    const short* __restrict__ W, const float* __restrict__ vis,
    short* __restrict__ out) {
  __shared__ alignas(16) short lW[32 * 512];   // 32 KB persistent
  __shared__ alignas(16) short lV[2][4376];    // ping-pong vis tile (skewed)
  const int tid = threadIdx.x;
  const int lane = tid & 63, w = tid >> 6;
  const int quad = lane >> 4, l16 = lane & 15;
  const int m0 = blockIdx.x * 32;
  const long n0 = (long)blockIdx.y * 128;
  const long b = blockIdx.z;
  const float* vb = vis + (b * 512) * 4096 + n0;

  // W-slab: round r stages row (w + 4r); slot=lane holds global chunk lane^(row&7)
#pragma unroll
  for (int r = 0; r < 8; r++) {
    const int row = w + 4 * r;
    load_lds16(&W[(m0 + row) * 512 + ((lane ^ (row & 7)) * 8)],
               &lW[row * 512 + lane * 8]);
  }

  const int vc = w * 8 + (lane >> 3);  // c within 32-tile (0..31)
  const int vs = (lane & 7) * 16;      // s within 128-chunk
  const int vofs = vc * 136 + (vc >> 3) * 8 + vs;

  float4v rg[2][4];  // 2-deep register pipeline of the vis stream
#pragma unroll
  for (int p = 0; p < 2; p++) {
    const float* src = vb + (long)(p * 32 + vc) * 4096 + vs;
#pragma unroll
    for (int q = 0; q < 4; q++) rg[p][q] = ((const float4v*)src)[q];
  }

  float4v acc[2][2];
#pragma unroll
  for (int i = 0; i < 2; i++)
#pragma unroll
    for (int j = 0; j < 2; j++) acc[i][j] = (float4v)0.0f;

  for (int kt = 0, it = 0; kt < 512; kt += 32, it++) {
    const int pb = it & 1;
    // convert + write this iter's vis tile (c-major, skewed)
    short8 c0, c1;
#pragma unroll
    for (int j = 0; j < 4; j++) {
      c0[j] = f2bf(rg[pb][0][j]);
      c0[4 + j] = f2bf(rg[pb][1][j]);
      c1[j] = f2bf(rg[pb][2][j]);
      c1[4 + j] = f2bf(rg[pb][3][j]);
    }
    *(short8*)&lV[pb][vofs] = c0;
    *(short8*)&lV[pb][vofs + 8] = c1;
    __syncthreads();  // tile(pb) visible; (it==0) also drains W async stage

    if (kt + 64 < 512) {  // refill this reg slot for iter it+2
      const float* src = vb + (long)(kt + 64 + vc) * 4096 + vs;
#pragma unroll
      for (int q = 0; q < 4; q++) rg[pb][q] = ((const float4v*)src)[q];
    }

    short8 af[2];
#pragma unroll
    for (int mt = 0; mt < 2; mt++) {
      const int ra = mt * 16 + l16;
      af[mt] = *(const short8*)&lW[ra * 512 + ((((kt >> 3) + quad) ^ (ra & 7)) * 8)];
    }
    short8 bf[2];
#pragma unroll
    for (int nt = 0; nt < 2; nt++) {
      const int sb = w * 32 + nt * 16 + l16;
#pragma unroll
      for (int j = 0; j < 8; j++) {
        const int c = quad * 8 + j;
        bf[nt][j] = lV[pb][c * 136 + (c >> 3) * 8 + sb];
      }
    }
#pragma unroll
    for (int mt = 0; mt < 2; mt++)
#pragma unroll
      for (int nt = 0; nt < 2; nt++)
        acc[mt][nt] = mfma16x16x32(af[mt], bf[nt], acc[mt][nt]);
    // no second barrier: next iter writes the OTHER lV buffer (ping-pong)
  }

  // C/D: col(s) = l16, row(i) = quad*4 + reg
  if (TRANS) {  // k[s][i]: pack 4 consecutive i as short4 (32-B runs per quad-group)
#pragma unroll
    for (int mt = 0; mt < 2; mt++)
#pragma unroll
      for (int nt = 0; nt < 2; nt++) {
        const long s = n0 + w * 32 + nt * 16 + l16;
        short4v pk;
#pragma unroll
        for (int r = 0; r < 4; r++) pk[r] = f2bf(acc[mt][nt][r]);
        *(short4v*)&out[(b * 4096 + s) * 512 + m0 + mt * 16 + quad * 4] = pk;
      }
  } else {  // v[i][s]
#pragma unroll
    for (int mt = 0; mt < 2; mt++)
#pragma unroll
      for (int nt = 0; nt < 2; nt++) {
        const long s = n0 + w * 32 + nt * 16 + l16;
#pragma unroll
        for (int r = 0; r < 4; r++)
          out[(b * 512 + m0 + mt * 16 + quad * 4 + r) * 4096 + s] = f2bf(acc[mt][nt][r]);
      }
  }
}

// ---------------- attention partial: block = (head, batch, s-chunk) ----------------
// Each block covers 4096/NCH s-positions; no-max softmax partials.
// XOR-swizzled LDS; k/v fragments hoisted to regs; prefetch-reordered.
__global__ __launch_bounds__(256) void attn_part(
    const short* __restrict__ q, const short* __restrict__ kws,
    const short* __restrict__ vws, float* __restrict__ Opart,
    float* __restrict__ lpart, int b0) {
  const int h = blockIdx.x;
  const int bz = blockIdx.y;
  const int ch = blockIdx.z;
  const int tid = threadIdx.x;
  const int lane = tid & 63, w = tid >> 6;
  const int quad = lane >> 4, l16 = lane & 15;

  __shared__ alignas(16) short lq[64 * 64];
  __shared__ alignas(16) short lk[128 * 64];
  __shared__ alignas(16) short lv[64 * 128];
  __shared__ alignas(16) short lp[64 * 128];
  __shared__ float lsum[64];

  const short* qb = q + ((long)(b0 + bz) * 64) * 512 + h * 64;
  const short* kb = kws + (long)bz * 4096 * 512 + h * 64;
  const short* vb = vws + (long)bz * 512 * 4096 + (long)h * 64 * 4096;

  if (tid < 64) lsum[tid] = 0.0f;
  {
    const int qr = tid >> 3;
    const int qc = ((tid & 7) ^ (qr & 7)) * 8;
    load_lds16(&qb[qr * 512 + qc], &lq[tid * 8]);
    load_lds16(&qb[(32 + qr) * 512 + qc], &lq[2048 + tid * 8]);
  }
  const int s0_first = ch * (4096 / NCH);
  const int send = s0_first + (4096 / NCH);
#pragma unroll
  for (int it = 0; it < 4; it++) {
    const int li = tid + it * 256;
    const int kr = li >> 3;
    const int kc = ((li & 7) ^ (kr & 7)) * 8;
    load_lds16(&kb[(long)(s0_first + kr) * 512 + kc], &lk[li * 8]);
  }
#pragma unroll
  for (int it = 0; it < 4; it++) {
    const int li = tid + it * 256;
    const int vr = li >> 4;
    const int vc = ((li & 15) ^ (vr & 7)) * 8;
    load_lds16(&vb[(long)vr * 4096 + s0_first + vc], &lv[li * 8]);
  }
  __syncthreads();

  short8 aq[4][2];
#pragma unroll
  for (int mt = 0; mt < 4; mt++)
#pragma unroll
    for (int ks = 0; ks < 2; ks++) {
      const int ra = mt * 16 + l16;
      aq[mt][ks] = *(const short8*)&lq[ra * 64 + (((ks * 4 + quad) ^ (ra & 7)) * 8)];
    }

  float4v osc[4];
#pragma unroll
  for (int mt = 0; mt < 4; mt++) osc[mt] = (float4v)0.0f;
  float lrow[4][4] = {};

  for (int s0 = s0_first; s0 < send; s0 += 128) {
    short8 bk[2][2];
#pragma unroll
    for (int ks = 0; ks < 2; ks++)
#pragma unroll
      for (int jn = 0; jn < 2; jn++) {
        const int rb = (2 * w + jn) * 16 + l16;
        bk[ks][jn] = *(const short8*)&lk[rb * 64 + (((ks * 4 + quad) ^ (rb & 7)) * 8)];
      }
    short8 bv[4];
#pragma unroll
    for (int ks = 0; ks < 4; ks++) {
      const int rv = w * 16 + l16;
      bv[ks] = *(const short8*)&lv[rv * 128 + (((ks * 4 + quad) ^ (rv & 7)) * 8)];
    }
    __syncthreads();

    if (s0 + 128 < send) {
#pragma unroll
      for (int it = 0; it < 4; it++) {
        const int li = tid + it * 256;
        const int kr = li >> 3;
        const int kc = ((li & 7) ^ (kr & 7)) * 8;
        load_lds16(&kb[(long)(s0 + 128 + kr) * 512 + kc], &lk[li * 8]);
      }
#pragma unroll
      for (int it = 0; it < 4; it++) {
        const int li = tid + it * 256;
        const int vr = li >> 4;
        const int vc = ((li & 15) ^ (vr & 7)) * 8;
        load_lds16(&vb[(long)vr * 4096 + s0 + 128 + vc], &lv[li * 8]);
      }
    }

    float4v sc[4][2];
#pragma unroll
    for (int mt = 0; mt < 4; mt++)
#pragma unroll
      for (int jn = 0; jn < 2; jn++) sc[mt][jn] = (float4v)0.0f;
#pragma unroll
    for (int ks = 0; ks < 2; ks++)
#pragma unroll
      for (int mt = 0; mt < 4; mt++)
#pragma unroll
        for (int jn = 0; jn < 2; jn++)
          sc[mt][jn] = mfma16x16x32(aq[mt][ks], bk[ks][jn], sc[mt][jn]);

#pragma unroll
    for (int mt = 0; mt < 4; mt++)
#pragma unroll
      for (int jn = 0; jn < 2; jn++)
#pragma unroll
        for (int r = 0; r < 4; r++) {
          const float scv = fminf(fmaxf(sc[mt][jn][r], -80.0f), 30.0f);
          const short sp = f2bf(__expf(scv));
          lrow[mt][r] += bf2f(sp);
          const int rowp = mt * 16 + quad * 4 + r;
          const int col = (2 * w + jn) * 16 + l16;
          lp[rowp * 128 + (((col >> 3) ^ (rowp & 7)) * 8) + (col & 7)] = sp;
        }
    __syncthreads();

#pragma unroll
    for (int ks = 0; ks < 4; ks++)
#pragma unroll
      for (int mt = 0; mt < 4; mt++) {
        const int rp = mt * 16 + l16;
        const short8 ap = *(const short8*)&lp[rp * 128 + (((ks * 4 + quad) ^ (rp & 7)) * 8)];
        osc[mt] = mfma16x16x32(ap, bv[ks], osc[mt]);
      }
    __syncthreads();
  }

#pragma unroll
  for (int mt = 0; mt < 4; mt++)
#pragma unroll
    for (int r = 0; r < 4; r++) {
      float v = lrow[mt][r];
      v += __shfl_xor(v, 1);
      v += __shfl_xor(v, 2);
      v += __shfl_xor(v, 4);
      v += __shfl_xor(v, 8);
      if (l16 == 0) atomicAdd(&lsum[mt * 16 + quad * 4 + r], v);
    }
  __syncthreads();

  const long bh = bz * 8 + h;
  float* op = Opart + ((bh * NCH + ch) * 64) * 64 + w * 16 + l16;
#pragma unroll
  for (int mt = 0; mt < 4; mt++)
#pragma unroll
    for (int r = 0; r < 4; r++)
      op[(long)(mt * 16 + quad * 4 + r) * 64] = osc[mt][r];
  if (tid < 64) lpart[(bh * NCH + ch) * 64 + tid] = lsum[tid];
}

// ---------------- combine attention partials -> tmp bf16 (b,t,i) ----------------
__global__ __launch_bounds__(256) void attn_combine(
    const float* __restrict__ Opart, const float* __restrict__ lpart,
    short* __restrict__ tmp, int b0, int nbh) {
  const int total = nbh * 4096;
  for (int idx = blockIdx.x * 256 + threadIdx.x; idx < total;
       idx += gridDim.x * 256) {
    const int bh = idx >> 12;
    const int td = idx & 4095;
    const int t = td >> 6, d = td & 63;
    float o = 0.0f, l = 0.0f;
#pragma unroll
    for (int c = 0; c < NCH; c++) {
      o += Opart[((long)bh * NCH + c) * 4096 + td];
      l += lpart[(bh * NCH + c) * 64 + t];
    }
    const int b = b0 + (bh >> 3), h = bh & 7;
    tmp[((long)b * 64 + t) * 512 + h * 64 + d] = f2bf(o / l);
  }
}

// ---------------- launch ----------------
extern "C" void kernel_launch(void* const* d_in, const int* in_sizes, int n_in,
                              void* d_out, int out_size, void* d_ws, size_t ws_size,
                              hipStream_t stream) {
  (void)in_sizes; (void)n_in; (void)out_size;
  const float* vis = (const float*)d_in[0];   // [16][512][4096] fp32
  const float* lang = (const float*)d_in[1];  // [16][64][512]  fp32
  const float* Wq = (const float*)d_in[3];    // [512][512] fp32
  const float* Wk = (const float*)d_in[4];
  const float* Wv = (const float*)d_in[5];
  const float* Wo = (const float*)d_in[6];
  float* out = (float*)d_out;                 // [16][64][512] fp32

  char* ws = (char*)d_ws;
  const size_t MB = 1 << 20;
  short* q_ws = (short*)(ws + 0 * MB);
  short* tmp_ws = (short*)(ws + 1 * MB);
  short* langb = (short*)(ws + 2 * MB);
  short* Wqb = (short*)(ws + 3 * MB);
  short* Wkb = (short*)(ws + 3 * MB + 512 * 1024);
  short* Wvb = (short*)(ws + 4 * MB);
  short* Wob = (short*)(ws + 4 * MB + 512 * 1024);
  char* grp = ws + 5 * MB;

  const long batch_elems = 4096l * 512;
  int g = 16;
  const int cands[5] = {1, 2, 4, 8, 16};
  for (int ci = 0; ci < 5; ci++) {
    const int Bgc = 16 / cands[ci];
    const size_t need = 5 * MB + 2ull * Bgc * batch_elems * 2          // k, v
                        + (size_t)Bgc * 8 * NCH * 4096 * 4 + (1 * MB);  // Opart + lpart
    if (need <= ws_size) { g = cands[ci]; break; }
  }
  const int Bg = 16 / g;
  short* k_ws = (short*)grp;                    // [Bg][4096][512] (s,i)
  short* v_ws = k_ws + (long)Bg * batch_elems;  // [Bg][512][4096] (i,s)
  float* Opart = (float*)(v_ws + (long)Bg * batch_elems);
  float* lptr = Opart + (long)Bg * 8 * NCH * 4096;

  convert5<<<dim3(128, 5), 256, 0, stream>>>(lang, langb, Wq, Wqb, Wk, Wkb,
                                             Wv, Wvb, Wo, Wob);

  // q = SCALE * lang @ Wq^T
  gemm_nt<0><<<dim3(4, 8), 256, 0, stream>>>(langb, Wqb, q_ws, 512, 512, 0.125f);

  for (int gi = 0; gi < g; gi++) {
    const int b0 = gi * Bg;
    const float* visg = vis + (long)b0 * 512 * 4096;
    proj_kv<1><<<dim3(16, 32, Bg), 256, 0, stream>>>(Wkb, visg, k_ws);
    proj_kv<0><<<dim3(16, 32, Bg), 256, 0, stream>>>(Wvb, visg, v_ws);
    attn_part<<<dim3(8, Bg, NCH), 256, 0, stream>>>(q_ws, k_ws, v_ws, Opart, lptr, b0);
    attn_combine<<<512, 256, 0, stream>>>(Opart, lptr, tmp_ws, b0, Bg * 8);
  }

  // out = tmp @ Wo^T, fp32 epilogue
  gemm_nt<1><<<dim3(4, 8), 256, 0, stream>>>(tmp_ws, Wob, out, 512, 512, 1.0f);
}